// Round 13
// baseline (22.455 us; speedup 1.0000x reference)
//
#include <hip/hip_runtime.h>
#include <hip/hip_bf16.h>

// out = value @ Wv + bv + key   (softmax over [.,.,1,1] is identically 1 -> ctx == v)
// M=2048, N=1024, K=1024
//
// ONE kernel. 128x64 tile, 512 threads (8 waves, 2x4), 2-buffer LDS,
// reg-staged f32->bf16 conversion (no pre-pass, no ws):
//   A: value f32, 16 f32/thread -> 8 pack2 -> 2 swizzled ds_write_b128
//   B: Wv f32 k-major, 8 f32/thread -> pack2 k-pairs -> 4 swizzled ds_write_b32
// R13: L2-fit XCD swizzle (4 bm2 x 8 bn per XCD = 4MB exactly), 3-deep register
// load pipeline (slack for vmcnt under cvtWrite), early key/bv prefetch (kt==8).
// One lgkmcnt(0)+s_barrier per K-step; vmcnt never drained in-loop.

#define M_DIM 2048
#define N_DIM 1024
#define K_DIM 1024

typedef __attribute__((ext_vector_type(8))) short short8;
typedef __attribute__((ext_vector_type(4))) float f32x4;

__device__ inline unsigned rne_bf16(float f) {
    unsigned u = __builtin_bit_cast(unsigned, f);
    return (u + 0x7FFFu + ((u >> 16) & 1u)) >> 16;
}
__device__ inline unsigned pack2(float lo, float hi) {
    return rne_bf16(lo) | (rne_bf16(hi) << 16);
}

__global__ __launch_bounds__(512)
void fused_gemm(const float* __restrict__ value, const float* __restrict__ Wv,
                const float* __restrict__ key, const float* __restrict__ bv,
                float* __restrict__ out) {
    __shared__ __align__(16) char smem[49152];
    short (*As)[8192] = (short (*)[8192])smem;             // 2 x 16 KB (128r x 64k bf16)
    short (*Bs)[4096] = (short (*)[4096])(smem + 32768);   // 2 x 8 KB  (64n x 64k bf16)

    const int tid = threadIdx.x, bid = blockIdx.x;
    // L2-fit XCD swizzle: XCD owns 4 bm2-bands x 8 bn -> A 2MB + B 2MB = 4MB L2.
    const int xcd = bid & 7, idx = bid >> 3;               // idx 0..31
    const int bm2 = (xcd & 3) * 4 + (idx >> 3);            // 0..15 (128-row band)
    const int bn  = (xcd >> 2) * 8 + (idx & 7);            // 0..15 (64-col band)
    const int row0 = bm2 * 128, col0 = bn * 64;
    const int lane = tid & 63, wid = tid >> 6;
    const int wr = wid >> 1, wc = wid & 1;  // wave: rows wr*32..+31, cols wc*32..+31

    // ---- staging coordinates
    const int rowA = tid >> 2;              // 0..127
    const int kq   = tid & 3;               // which 16-f32 slab of the 64-k tile
    const float* aptr = value + (size_t)(row0 + rowA) * K_DIM + kq * 16;
    const int kp = tid >> 4;                // 0..31 (k-pair within tile)
    const int n4 = (tid & 15) * 4;
    const float* bptr = Wv + (size_t)(2 * kp) * N_DIM + col0 + n4;

    f32x4 sa[3][4];   // three reg slots (kt % 3), 16 A f32 each
    f32x4 sb[3][2];   // 8 B f32 each (k rows 2kp, 2kp+1)

    auto loadT = [&](int s, int kt) {
        const float* ap = aptr + kt * 64;
        sa[s][0] = *(const f32x4*)(ap + 0);
        sa[s][1] = *(const f32x4*)(ap + 4);
        sa[s][2] = *(const f32x4*)(ap + 8);
        sa[s][3] = *(const f32x4*)(ap + 12);
        const float* bp = bptr + (size_t)kt * 64 * N_DIM;
        sb[s][0] = *(const f32x4*)bp;
        sb[s][1] = *(const f32x4*)(bp + N_DIM);
    };

    auto cvtWrite = [&](int s, int buf) {
        union { short8 v; unsigned u[4]; } c0, c1;
        c0.u[0] = pack2(sa[s][0][0], sa[s][0][1]);
        c0.u[1] = pack2(sa[s][0][2], sa[s][0][3]);
        c0.u[2] = pack2(sa[s][1][0], sa[s][1][1]);
        c0.u[3] = pack2(sa[s][1][2], sa[s][1][3]);
        c1.u[0] = pack2(sa[s][2][0], sa[s][2][1]);
        c1.u[1] = pack2(sa[s][2][2], sa[s][2][3]);
        c1.u[2] = pack2(sa[s][3][0], sa[s][3][1]);
        c1.u[3] = pack2(sa[s][3][2], sa[s][3][3]);
        const int sw = rowA & 7;
        *(short8*)&As[buf][rowA * 64 + (((kq * 2)     ^ sw) << 3)] = c0.v;
        *(short8*)&As[buf][rowA * 64 + (((kq * 2 + 1) ^ sw) << 3)] = c1.v;
        unsigned* bu = (unsigned*)&Bs[buf][0];
        #pragma unroll
        for (int m = 0; m < 4; ++m) {
            unsigned u = pack2(sb[s][0][m], sb[s][1][m]);  // (k even, k odd)
            int n = n4 + m;
            int chB = (kp >> 2) ^ ((n >> 1) & 7);
            bu[n * 32 + (chB << 2) + (kp & 3)] = u;
        }
    };

    f32x4 acc[2][2] = {};
    auto compute = [&](int buf) {
        #pragma unroll
        for (int ks = 0; ks < 2; ++ks) {
            short8 afr[2], bfr[2];
            const int g = ks * 4 + (lane >> 4);
            #pragma unroll
            for (int fm = 0; fm < 2; ++fm) {
                int r = wr * 32 + fm * 16 + (lane & 15);
                afr[fm] = *(const short8*)&As[buf][r * 64 + ((g ^ (r & 7)) << 3)];
            }
            #pragma unroll
            for (int fn = 0; fn < 2; ++fn) {
                int n = wc * 32 + fn * 16 + (lane & 15);
                bfr[fn] = *(const short8*)&Bs[buf][n * 64 + ((g ^ ((n >> 1) & 7)) << 3)];
            }
            #pragma unroll
            for (int fm = 0; fm < 2; ++fm)
                #pragma unroll
                for (int fn = 0; fn < 2; ++fn)
                    acc[fm][fn] = __builtin_amdgcn_mfma_f32_16x16x32_bf16(
                        afr[fm], bfr[fn], acc[fm][fn], 0, 0, 0);
        }
    };

    // epilogue prefetch regs
    f32x4 kr[4];
    f32x4 br;
    const int rE = tid >> 4;                // 0..31
    const int cE = (tid & 15) * 4;          // 0..60

    // ---- prologue: T0..T2 in regs; T0 -> LDS buf0
    loadT(0, 0);
    loadT(1, 1);
    loadT(2, 2);
    cvtWrite(0, 0);
    asm volatile("s_waitcnt lgkmcnt(0)" ::: "memory");
    __builtin_amdgcn_s_barrier();
    __builtin_amdgcn_sched_barrier(0);

    // ---- main loop: one barrier per K-step; vmcnt never drained in-loop.
    // Slot s=kt%3 holds tile kt: loaded at step kt-3, LDS-written at step kt-1,
    // computed at step kt.
    #pragma unroll
    for (int kt = 0; kt < 16; ++kt) {
        const int buf = kt & 1;
        if (kt + 3 < 16) loadT((kt + 3) % 3, kt + 3);
        compute(buf);                               // tile kt from LDS
        if (kt + 1 < 16) cvtWrite((kt + 1) % 3, buf ^ 1);
        if (kt == 8) {                              // key/bv prefetch (HBM-cold)
            #pragma unroll
            for (int it = 0; it < 4; ++it)
                kr[it] = *(const f32x4*)&key[(size_t)(row0 + it * 32 + rE) * N_DIM + col0 + cE];
            br = *(const f32x4*)&bv[col0 + cE];
        }
        asm volatile("s_waitcnt lgkmcnt(0)" ::: "memory");
        __builtin_amdgcn_s_barrier();
        __builtin_amdgcn_sched_barrier(0);
    }

    // ---- epilogue: acc -> LDS transpose (reuses all smem) -> coalesced f32x4
    float* T = (float*)smem;                // 128 x 68 f32 = 34.8 KB <= 48 KB
    #pragma unroll
    for (int fm = 0; fm < 2; ++fm)
        #pragma unroll
        for (int fn = 0; fn < 2; ++fn) {
            int c = wc * 32 + fn * 16 + (lane & 15);
            #pragma unroll
            for (int i = 0; i < 4; ++i) {
                int r = wr * 32 + fm * 16 + (lane >> 4) * 4 + i;
                T[r * 68 + c] = acc[fm][fn][i];
            }
        }
    asm volatile("s_waitcnt lgkmcnt(0)" ::: "memory");
    __builtin_amdgcn_s_barrier();
    #pragma unroll
    for (int it = 0; it < 4; ++it) {
        int r = it * 32 + rE;
        f32x4 vv = *(f32x4*)&T[r * 68 + cE];
        vv = vv + kr[it] + br;
        *(f32x4*)&out[(size_t)(row0 + r) * N_DIM + col0 + cE] = vv;
    }
}

extern "C" void kernel_launch(void* const* d_in, const int* in_sizes, int n_in,
                              void* d_out, int out_size, void* d_ws, size_t ws_size,
                              hipStream_t stream) {
    // setup_inputs order: 0 query, 1 key, 2 value, 3 Wq, 4 bq, 5 Wk, 6 bk, 7 Wv, 8 bv, 9 U
    const float* key   = (const float*)d_in[1];
    const float* value = (const float*)d_in[2];
    const float* Wv    = (const float*)d_in[7];
    const float* bv    = (const float*)d_in[8];
    float* out = (float*)d_out;

    fused_gemm<<<256, 512, 0, stream>>>(value, Wv, key, bv, out);
}

// Round 14
// 21.623 us; speedup vs baseline: 1.0385x; 1.0385x over previous
//
#include <hip/hip_runtime.h>
#include <hip/hip_bf16.h>

// out = value @ Wv + bv + key   (softmax over [.,.,1,1] is identically 1 -> ctx == v)
// M=2048, N=1024, K=1024
//
// ONE kernel (R12 structure = best, 21.4us). 128x64 tile, 512 threads (8 waves,
// 2x4), 2-buffer LDS, reg-staged f32->bf16 conversion in the staging path.
// R14 deltas vs R12: 4-deep register load pipeline (slot = kt&3, static), and
// B(Wv) loads issued BEFORE A loads each step (B is the cross-XCD/L3 stream).
// One lgkmcnt(0)+s_barrier per K-step; vmcnt never drained in-loop.

#define M_DIM 2048
#define N_DIM 1024
#define K_DIM 1024

typedef __attribute__((ext_vector_type(8))) short short8;
typedef __attribute__((ext_vector_type(4))) float f32x4;

__device__ inline unsigned rne_bf16(float f) {
    unsigned u = __builtin_bit_cast(unsigned, f);
    return (u + 0x7FFFu + ((u >> 16) & 1u)) >> 16;
}
__device__ inline unsigned pack2(float lo, float hi) {
    return rne_bf16(lo) | (rne_bf16(hi) << 16);
}

__global__ __launch_bounds__(512)
void fused_gemm(const float* __restrict__ value, const float* __restrict__ Wv,
                const float* __restrict__ key, const float* __restrict__ bv,
                float* __restrict__ out) {
    __shared__ __align__(16) char smem[49152];
    short (*As)[8192] = (short (*)[8192])smem;             // 2 x 16 KB (128r x 64k bf16)
    short (*Bs)[4096] = (short (*)[4096])(smem + 32768);   // 2 x 8 KB  (64n x 64k bf16)

    const int tid = threadIdx.x, bid = blockIdx.x;
    // R12 XCD swizzle (best measured): xcd owns 2 bm2-bands x 16 bn.
    const int xcd = bid & 7, idx = bid >> 3;
    const int bm2 = xcd * 2 + (idx >> 4);   // 0..15 (128-row band)
    const int bn  = idx & 15;               // 0..15 (64-col band)
    const int row0 = bm2 * 128, col0 = bn * 64;
    const int lane = tid & 63, wid = tid >> 6;
    const int wr = wid >> 1, wc = wid & 1;  // wave: rows wr*32..+31, cols wc*32..+31

    // ---- staging coordinates
    const int rowA = tid >> 2;              // 0..127
    const int kq   = tid & 3;               // which 16-f32 slab of the 64-k tile
    const float* aptr = value + (size_t)(row0 + rowA) * K_DIM + kq * 16;
    const int kp = tid >> 4;                // 0..31 (k-pair within tile)
    const int n4 = (tid & 15) * 4;
    const float* bptr = Wv + (size_t)(2 * kp) * N_DIM + col0 + n4;

    f32x4 sa[4][4];   // four reg slots (kt & 3), 16 A f32 each
    f32x4 sb[4][2];   // 8 B f32 each (k rows 2kp, 2kp+1)

    auto loadT = [&](int s, int kt) {
        // B first: L3-served cross-XCD stream -> give it the longest lead time.
        const float* bp = bptr + (size_t)kt * 64 * N_DIM;
        sb[s][0] = *(const f32x4*)bp;
        sb[s][1] = *(const f32x4*)(bp + N_DIM);
        const float* ap = aptr + kt * 64;
        sa[s][0] = *(const f32x4*)(ap + 0);
        sa[s][1] = *(const f32x4*)(ap + 4);
        sa[s][2] = *(const f32x4*)(ap + 8);
        sa[s][3] = *(const f32x4*)(ap + 12);
    };

    auto cvtWrite = [&](int s, int buf) {
        union { short8 v; unsigned u[4]; } c0, c1;
        c0.u[0] = pack2(sa[s][0][0], sa[s][0][1]);
        c0.u[1] = pack2(sa[s][0][2], sa[s][0][3]);
        c0.u[2] = pack2(sa[s][1][0], sa[s][1][1]);
        c0.u[3] = pack2(sa[s][1][2], sa[s][1][3]);
        c1.u[0] = pack2(sa[s][2][0], sa[s][2][1]);
        c1.u[1] = pack2(sa[s][2][2], sa[s][2][3]);
        c1.u[2] = pack2(sa[s][3][0], sa[s][3][1]);
        c1.u[3] = pack2(sa[s][3][2], sa[s][3][3]);
        const int sw = rowA & 7;
        *(short8*)&As[buf][rowA * 64 + (((kq * 2)     ^ sw) << 3)] = c0.v;
        *(short8*)&As[buf][rowA * 64 + (((kq * 2 + 1) ^ sw) << 3)] = c1.v;
        unsigned* bu = (unsigned*)&Bs[buf][0];
        #pragma unroll
        for (int m = 0; m < 4; ++m) {
            unsigned u = pack2(sb[s][0][m], sb[s][1][m]);  // (k even, k odd)
            int n = n4 + m;
            int chB = (kp >> 2) ^ ((n >> 1) & 7);
            bu[n * 32 + (chB << 2) + (kp & 3)] = u;
        }
    };

    f32x4 acc[2][2] = {};
    auto compute = [&](int buf) {
        #pragma unroll
        for (int ks = 0; ks < 2; ++ks) {
            short8 afr[2], bfr[2];
            const int g = ks * 4 + (lane >> 4);
            #pragma unroll
            for (int fm = 0; fm < 2; ++fm) {
                int r = wr * 32 + fm * 16 + (lane & 15);
                afr[fm] = *(const short8*)&As[buf][r * 64 + ((g ^ (r & 7)) << 3)];
            }
            #pragma unroll
            for (int fn = 0; fn < 2; ++fn) {
                int n = wc * 32 + fn * 16 + (lane & 15);
                bfr[fn] = *(const short8*)&Bs[buf][n * 64 + ((g ^ ((n >> 1) & 7)) << 3)];
            }
            #pragma unroll
            for (int fm = 0; fm < 2; ++fm)
                #pragma unroll
                for (int fn = 0; fn < 2; ++fn)
                    acc[fm][fn] = __builtin_amdgcn_mfma_f32_16x16x32_bf16(
                        afr[fm], bfr[fn], acc[fm][fn], 0, 0, 0);
        }
    };

    // epilogue prefetch regs
    f32x4 kr[4];
    f32x4 br;
    const int rE = tid >> 4;                // 0..31
    const int cE = (tid & 15) * 4;          // 0..60

    // ---- prologue: T0..T3 in regs; T0 -> LDS buf0
    loadT(0, 0);
    loadT(1, 1);
    loadT(2, 2);
    loadT(3, 3);
    cvtWrite(0, 0);
    asm volatile("s_waitcnt lgkmcnt(0)" ::: "memory");
    __builtin_amdgcn_s_barrier();
    __builtin_amdgcn_sched_barrier(0);

    // ---- main loop: one barrier per K-step; vmcnt never drained in-loop.
    // Slot s=kt&3 holds tile kt: loaded at step kt-4, LDS-written at step kt-1,
    // computed at step kt.
    #pragma unroll
    for (int kt = 0; kt < 16; ++kt) {
        const int buf = kt & 1;
        if (kt + 4 < 16) loadT((kt + 4) & 3, kt + 4);
        compute(buf);                               // tile kt from LDS
        if (kt + 1 < 16) cvtWrite((kt + 1) & 3, buf ^ 1);
        if (kt == 8) {                              // key/bv prefetch (HBM-cold)
            #pragma unroll
            for (int it = 0; it < 4; ++it)
                kr[it] = *(const f32x4*)&key[(size_t)(row0 + it * 32 + rE) * N_DIM + col0 + cE];
            br = *(const f32x4*)&bv[col0 + cE];
        }
        asm volatile("s_waitcnt lgkmcnt(0)" ::: "memory");
        __builtin_amdgcn_s_barrier();
        __builtin_amdgcn_sched_barrier(0);
    }

    // ---- epilogue: acc -> LDS transpose (reuses all smem) -> coalesced f32x4
    float* T = (float*)smem;                // 128 x 68 f32 = 34.8 KB <= 48 KB
    #pragma unroll
    for (int fm = 0; fm < 2; ++fm)
        #pragma unroll
        for (int fn = 0; fn < 2; ++fn) {
            int c = wc * 32 + fn * 16 + (lane & 15);
            #pragma unroll
            for (int i = 0; i < 4; ++i) {
                int r = wr * 32 + fm * 16 + (lane >> 4) * 4 + i;
                T[r * 68 + c] = acc[fm][fn][i];
            }
        }
    asm volatile("s_waitcnt lgkmcnt(0)" ::: "memory");
    __builtin_amdgcn_s_barrier();
    #pragma unroll
    for (int it = 0; it < 4; ++it) {
        int r = it * 32 + rE;
        f32x4 vv = *(f32x4*)&T[r * 68 + cE];
        vv = vv + kr[it] + br;
        *(f32x4*)&out[(size_t)(row0 + r) * N_DIM + col0 + cE] = vv;
    }
}

extern "C" void kernel_launch(void* const* d_in, const int* in_sizes, int n_in,
                              void* d_out, int out_size, void* d_ws, size_t ws_size,
                              hipStream_t stream) {
    // setup_inputs order: 0 query, 1 key, 2 value, 3 Wq, 4 bq, 5 Wk, 6 bk, 7 Wv, 8 bv, 9 U
    const float* key   = (const float*)d_in[1];
    const float* value = (const float*)d_in[2];
    const float* Wv    = (const float*)d_in[7];
    const float* bv    = (const float*)d_in[8];
    float* out = (float*)d_out;

    fused_gemm<<<256, 512, 0, stream>>>(value, Wv, key, bv, out);
}